// Round 5
// baseline (1315.011 us; speedup 1.0000x reference)
//
#include <hip/hip_runtime.h>
#include <math.h>

#define MU_F 0.1f
#define SHRINK_F 0.01f   // LMBD * MU
#define BN_EPS_F 1e-5f

typedef _Float16 half_t;
typedef _Float16 half8 __attribute__((ext_vector_type(8)));
typedef _Float16 half4 __attribute__((ext_vector_type(4)));
typedef float f32x4 __attribute__((ext_vector_type(4)));

// ---------------------------------------------------------------------------
// LDS-free register-fragment MFMA implicit-GEMM conv.
//   - A (weights) pre-packed in exact MFMA A-frag order:
//       Af[g][kc][m][lane][8]  value = W[g*64+m*16+(l&15)][kc*32+(l>>4)*8+j]
//     -> one coalesced 1KB dwordx4 per fragment, L1/L2 resident.
//   - B (activations, NHWC fp16) loaded directly in frag order: lane l reads
//     16B at pixel (p0+t*16+(l&15)), channels c0+(l>>4)*8.. (contiguous).
//   - NO LDS, NO barriers: K-loop fully unrolled (taps x chunks), compiler
//     pipelines loads arbitrarily deep (fine-grained vmcnt, hipBLASLt-style).
//   - Border taps: per-lane pointer select to a zero page (no exec churn).
//   - Flat (n,px) pixel space: 25088 px = 196 tiles of 128, zero padding.
// Block 256 thr = 4 waves: wave -> (co-group = y*2 + (wv&1), px-half = wv>>1).
// MODE 0 fwd conv stride S pad PAD; MODE 1 convT s1; MODE 2 convT s2 via
// parity quadrants (blockIdx.x = q*ptiles + tile), uniform tap skip.
// Frag layout m89-verified: A row=l&15,k=(l>>4)*8+j; C/D col=l&15,row=(l>>4)*4+r.
// ---------------------------------------------------------------------------
template<int KS, int S, int PAD, int MODE, int CAT>
__global__ __launch_bounds__(256)
void conv_reg(const half_t* __restrict__ Af, const half_t* __restrict__ Xh,
              float* __restrict__ outF, half_t* __restrict__ outH,
              const half_t* __restrict__ auxH, const half_t* __restrict__ aux3H,
              const float* __restrict__ pscale, const float* __restrict__ pbias,
              const half_t* __restrict__ zpage,
              int Cout, int Hin, int Win, int Hout, int Wout, int KT, int ptiles,
              float alpha, float beta, float delta, int relu1, int relu2)
{
    const int tid = threadIdx.x;
    const int wv = tid >> 6, ln = tid & 63;
    const int g  = blockIdx.y * 2 + (wv & 1);
    const int fr = ln & 15, rg = ln >> 4, ko8 = rg * 8;
    const int PXTOT = 25088;                     // 32 images x 784 (exact tiling)

    int eh = 0, ew = 0, bx = blockIdx.x;
    if (MODE == 2) { int q = bx / ptiles; bx -= q * ptiles; eh = q >> 1; ew = q & 1; }
    const int p0 = bx * 128 + (wv >> 1) * 64;

    const int Wd   = (MODE == 2) ? (Wout >> 1) : Wout;   // 28 everywhere here
    const int Hd   = (MODE == 2) ? (Hout >> 1) : Hout;
    const int PHWI = Hd * Wd;                            // px per image (784)

    int phv[4], pwv[4], nv[4];
    unsigned vb[4];                               // per-lane base offset (halves)
#pragma unroll
    for (int t = 0; t < 4; ++t) {
        int px = p0 + t * 16 + fr;                // < PXTOT by construction
        int n  = px / PHWI; int rem = px - n * PHWI;
        int ph = rem / Wd;  int pw  = rem - ph * Wd;
        nv[t] = n; phv[t] = ph; pwv[t] = pw;
        int ih0 = (MODE == 0) ? ph * S : ph;
        int iw0 = (MODE == 0) ? pw * S : pw;
        vb[t] = ((unsigned)(n * Hin + ih0) * Win + iw0) * CAT + ko8;
    }

    const half_t* Ap = Af + ((size_t)g * KT) * 2048 + ln * 8;
    f32x4 acc[4][4] = {};
    constexpr int cpt = CAT / 32;                 // chunks per tap

#pragma unroll
    for (int kh = 0; kh < KS; ++kh)
#pragma unroll
    for (int kw = 0; kw < KS; ++kw) {
        int dh, dw;
        if (MODE == 0)      { dh = kh - PAD; dw = kw - PAD; }
        else if (MODE == 1) { dh = PAD - kh; dw = PAD - kw; }
        else {
            if ((((kh ^ (eh + 1)) & 1) != 0) || (((kw ^ (ew + 1)) & 1) != 0)) continue;
            dh = (eh + PAD - kh) >> 1; dw = (ew + PAD - kw) >> 1;
        }
        const int off = (dh * Win + dw) * CAT;
        const half_t* bp[4];
#pragma unroll
        for (int t = 0; t < 4; ++t) {
            int ih = ((MODE == 0) ? phv[t] * S : phv[t]) + dh;
            int iw = ((MODE == 0) ? pwv[t] * S : pwv[t]) + dw;
            bool ok = (unsigned)ih < (unsigned)Hin && (unsigned)iw < (unsigned)Win;
            bp[t] = ok ? (Xh + vb[t] + off) : zpage;     // zero page: load-safe
        }
        const int tap = kh * KS + kw;
        const half_t* Apt = Ap + (size_t)(tap * cpt) * 2048;
#pragma unroll
        for (int ci = 0; ci < cpt; ++ci) {
            half8 fa[4], fb[4];
#pragma unroll
            for (int m = 0; m < 4; ++m)
                fa[m] = *(const half8*)(Apt + ci * 2048 + m * 512);
#pragma unroll
            for (int t = 0; t < 4; ++t)
                fb[t] = *(const half8*)(bp[t] + ci * 32);
#pragma unroll
            for (int m = 0; m < 4; ++m)
#pragma unroll
                for (int t = 0; t < 4; ++t)
                    acc[m][t] = __builtin_amdgcn_mfma_f32_16x16x32_f16(fa[m], fb[t], acc[m][t], 0, 0, 0);
        }
    }

    // epilogue: v = alpha*acc + delta (+beta*auxH); relu1; BN-fold; +aux3H; relu2
#pragma unroll
    for (int t = 0; t < 4; ++t) {
        int oh, ow;
        if (MODE == 2) { oh = 2 * phv[t] + eh; ow = 2 * pwv[t] + ew; }
        else           { oh = phv[t];          ow = pwv[t]; }
        size_t gb = ((size_t)(nv[t] * Hout + oh) * Wout + ow) * Cout + g * 64;
#pragma unroll
        for (int m = 0; m < 4; ++m) {
            const int cb = m * 16 + rg * 4;
            float v[4];
#pragma unroll
            for (int r = 0; r < 4; ++r) v[r] = alpha * acc[m][t][r] + delta;
            if (auxH) {
                half4 a1 = *(const half4*)(auxH + gb + cb);
#pragma unroll
                for (int r = 0; r < 4; ++r) v[r] += beta * (float)a1[r];
            }
            if (relu1)
#pragma unroll
                for (int r = 0; r < 4; ++r) v[r] = fmaxf(v[r], 0.f);
            if (pscale) {
                f32x4 s = *(const f32x4*)(pscale + g * 64 + cb);
                f32x4 b = *(const f32x4*)(pbias  + g * 64 + cb);
#pragma unroll
                for (int r = 0; r < 4; ++r) v[r] = s[r] * v[r] + b[r];
            }
            if (aux3H) {
                half4 a3 = *(const half4*)(aux3H + gb + cb);
#pragma unroll
                for (int r = 0; r < 4; ++r) v[r] += (float)a3[r];
            }
            if (relu2)
#pragma unroll
                for (int r = 0; r < 4; ++r) v[r] = fmaxf(v[r], 0.f);
            if (outH) {
                half4 o;
#pragma unroll
                for (int r = 0; r < 4; ++r) o[r] = (half_t)v[r];
                *(half4*)(outH + gb + cb) = o;
            } else {
                const int co = g * 64 + cb;
#pragma unroll
                for (int r = 0; r < 4; ++r)
                    outF[((size_t)(nv[t] * Cout + co + r) * Hout + oh) * Wout + ow] = v[r];
            }
        }
    }
}

// normalize (optional) + flat fp16 pack: Wh[row=co][tap][ci], WTh[row=ci][tap][co]
template<int KT>
__global__ __launch_bounds__(256)
void pack_w(const float* __restrict__ W, half_t* __restrict__ Wh,
            half_t* __restrict__ WTh, int Cin, int Cout, int do_norm)
{
    __shared__ float red[256];
    int co = blockIdx.x, tid = threadIdx.x;
    int CK = Cin * KT;
    const float* w = W + (size_t)co * CK;
    float inv = 1.f;
    if (do_norm) {
        float s = 0.f;
        for (int i = tid; i < CK; i += 256) { float v = w[i]; s += v * v; }
        red[tid] = s; __syncthreads();
        for (int o = 128; o > 0; o >>= 1) {
            if (tid < o) red[tid] += red[tid + o];
            __syncthreads();
        }
        inv = 1.f / (sqrtf(red[0]) + 1e-12f);
    }
    for (int i = tid; i < CK; i += 256) {
        int ci = i / KT, tap = i - ci * KT;
        half_t h = (half_t)(w[i] * inv);
        Wh[((size_t)co * KT + tap) * Cin + ci] = h;
        if (WTh) WTh[((size_t)ci * KT + tap) * Cout + co] = h;
    }
}

// flat [row][K9] -> MFMA A-frag order Af[g][kc][m][lane][8]
__global__ __launch_bounds__(256)
void pack_frag(const half_t* __restrict__ Wflat, half_t* __restrict__ Af,
               int KT, int total8)
{
    int idx = blockIdx.x * 256 + threadIdx.x;
    if (idx >= total8) return;
    int l = idx & 63, m = (idx >> 6) & 3, t2 = idx >> 8;
    int kc = t2 % KT, gg = t2 / KT;
    int row = gg * 64 + m * 16 + (l & 15);
    int koff = kc * 32 + (l >> 4) * 8;
    int K9 = KT * 32;
    *(half8*)(Af + (size_t)idx * 8) = *(const half8*)(Wflat + (size_t)row * K9 + koff);
}

// x (32,128,56,56) NCHW fp32 -> NHWC fp16
__global__ __launch_bounds__(256)
void tx_kernel(const float* __restrict__ x, half_t* __restrict__ xTh)
{
    __shared__ __align__(16) half_t tl[56 * 136];
    int h = blockIdx.x, n = blockIdx.y, tid = threadIdx.x;
    for (int it = 0; it < 28; ++it) {
        int id = tid + it * 256;
        int c = id / 56, w0 = id - c * 56;
        tl[w0 * 136 + c] = (half_t)x[(((size_t)n * 128 + c) * 56 + h) * 56 + w0];
    }
    __syncthreads();
    if (tid < 224) {
        int w0 = tid >> 2, part = tid & 3;
        size_t base = (((size_t)n * 56 + h) * 56 + w0) * 128 + part * 32;
#pragma unroll
        for (int j = 0; j < 4; ++j)
            *(half8*)(xTh + base + j * 8) = *(const half8*)(tl + w0 * 136 + part * 32 + j * 8);
    }
}

__global__ __launch_bounds__(256)
void comb_kernel(const half_t* __restrict__ c, const half_t* __restrict__ p,
                 half_t* __restrict__ a, float w1, float w2, int n8)
{
    int i = blockIdx.x * 256 + threadIdx.x;
    if (i >= n8) return;
    half8 cv = ((const half8*)c)[i];
    half8 pv = ((const half8*)p)[i];
    half8 r;
#pragma unroll
    for (int j = 0; j < 8; ++j) r[j] = (half_t)(w1 * (float)cv[j] + w2 * (float)pv[j]);
    ((half8*)a)[i] = r;
}

__global__ __launch_bounds__(256)
void bn_prep_kernel(const float* __restrict__ g, const float* __restrict__ b,
                    const float* __restrict__ m, const float* __restrict__ v,
                    float* __restrict__ s, float* __restrict__ t, int C)
{
    int i = blockIdx.x * 256 + threadIdx.x;
    if (i < C) {
        float sc = g[i] * rsqrtf(v[i] + BN_EPS_F);
        s[i] = sc; t[i] = b[i] - m[i] * sc;
    }
}

__global__ __launch_bounds__(256)
void zero_kernel(half_t* __restrict__ p, int n)
{
    int i = blockIdx.x * 256 + threadIdx.x;
    if (i < n) p[i] = (half_t)0.f;
}

extern "C" void kernel_launch(void* const* d_in, const int* in_sizes, int n_in,
                              void* d_out, int out_size, void* d_ws, size_t ws_size,
                              hipStream_t stream)
{
    (void)in_sizes; (void)n_in; (void)out_size;
    const float* x    = (const float*)d_in[0];
    const float* W1   = (const float*)d_in[1];
    const float* W2   = (const float*)d_in[2];
    const float* Wsc  = (const float*)d_in[3];
    const float* bn1g = (const float*)d_in[4];
    const float* bn1b = (const float*)d_in[5];
    const float* bn1m = (const float*)d_in[6];
    const float* bn1v = (const float*)d_in[7];
    const float* bn2g = (const float*)d_in[8];
    const float* bn2b = (const float*)d_in[9];
    const float* bn2m = (const float*)d_in[10];
    const float* bn2v = (const float*)d_in[11];
    const float* bscg = (const float*)d_in[12];
    const float* bscb = (const float*)d_in[13];
    const float* bscm = (const float*)d_in[14];
    const float* bscv = (const float*)d_in[15];

    const size_t NB = (size_t)32 * 256 * 28 * 28;   // 6,422,528
    const size_t NX = (size_t)32 * 128 * 56 * 56;   // 12,845,056

    char* base = (char*)d_ws;
    size_t off = 0;
    auto alloc = [&](size_t nbytes) -> void* {
        void* r = base + off;
        off = (off + nbytes + 255) & ~(size_t)255;
        return r;
    };
    // flat fp16 weights (pack_w output)
    half_t* Wh1  = (half_t*)alloc(294912 * 2);
    half_t* WTh1 = (half_t*)alloc(294912 * 2);
    half_t* Wh2  = (half_t*)alloc(589824 * 2);
    half_t* WTh2 = (half_t*)alloc(589824 * 2);
    half_t* Wsch = (half_t*)alloc(32768 * 2);
    // A-frag packs
    half_t* Af1  = (half_t*)alloc(294912 * 2);   // G4 KT36
    half_t* AfT1 = (half_t*)alloc(294912 * 2);   // G2 KT72
    half_t* Af2  = (half_t*)alloc(589824 * 2);   // G4 KT72
    half_t* AfT2 = (half_t*)alloc(589824 * 2);   // G4 KT72
    half_t* Afsc = (half_t*)alloc(32768 * 2);    // G4 KT4
    float* bn1s = (float*)alloc(256 * 4);  float* bn1t = (float*)alloc(256 * 4);
    float* bn2s = (float*)alloc(256 * 4);  float* bn2t = (float*)alloc(256 * 4);
    float* bscs = (float*)alloc(256 * 4);  float* bsct = (float*)alloc(256 * 4);
    half_t* zp   = (half_t*)alloc(512 * 2);      // zero page for border taps
    half_t* xTh  = (half_t*)alloc(NX * 2);       // persistent NHWC fp16 x
    half_t* r56h = (half_t*)alloc(NX * 2);
    half_t* Pa   = (half_t*)alloc(NB * 2);
    half_t* Pb   = (half_t*)alloc(NB * 2);
    half_t* Pc   = (half_t*)alloc(NB * 2);
    half_t* Py   = (half_t*)alloc(NB * 2);
    half_t* r28h = (half_t*)alloc(NB * 2);
    half_t* Psc  = (half_t*)alloc(NB * 2);
    if (off > ws_size) return;   // workspace too small -> fail loudly

    float* outp = (float*)d_out;

    // FISTA momentum coefficients (data-independent); al[0]==0 -> iter1 a==c
    double t = 1.0; float al[3];
    for (int i = 0; i < 3; ++i) {
        double tn = (1.0 + sqrt(1.0 + 4.0 * t * t)) / 2.0;
        al[i] = (float)((t - 1.0) / tn); t = tn;
    }

    const dim3 blk(256);
    const dim3 gF(196, 2);     // fwd / convT-s1: 25088 px / 128, 256 co / 128
    const dim3 gT2(784, 1);    // MODE2: 4 quadrants x 196 tiles, 128 co
    const int n8 = (int)(NB / 8);
    const dim3 gC((n8 + 255) / 256);
    const float* NF = nullptr;
    const half_t* NH = nullptr;
    float* NFo = nullptr;
    half_t* NHo = nullptr;

    // ---- prep ----
    pack_w<9><<<256, blk, 0, stream>>>(W1, Wh1, WTh1, 128, 256, 1);
    pack_w<9><<<256, blk, 0, stream>>>(W2, Wh2, WTh2, 256, 256, 1);
    pack_w<1><<<256, blk, 0, stream>>>(Wsc, Wsch, nullptr, 128, 256, 0);
    pack_frag<<<(36864 + 255) / 256, blk, 0, stream>>>(Wh1,  Af1,  36, 36864);
    pack_frag<<<(36864 + 255) / 256, blk, 0, stream>>>(WTh1, AfT1, 72, 36864);
    pack_frag<<<(73728 + 255) / 256, blk, 0, stream>>>(Wh2,  Af2,  72, 73728);
    pack_frag<<<(73728 + 255) / 256, blk, 0, stream>>>(WTh2, AfT2, 72, 73728);
    pack_frag<<<(4096  + 255) / 256, blk, 0, stream>>>(Wsch, Afsc,  4, 4096);
    bn_prep_kernel<<<1, blk, 0, stream>>>(bn1g, bn1b, bn1m, bn1v, bn1s, bn1t, 256);
    bn_prep_kernel<<<1, blk, 0, stream>>>(bn2g, bn2b, bn2m, bn2v, bn2s, bn2t, 256);
    bn_prep_kernel<<<1, blk, 0, stream>>>(bscg, bscb, bscm, bscv, bscs, bsct, 256);
    zero_kernel<<<2, blk, 0, stream>>>(zp, 512);
    tx_kernel<<<dim3(56, 32), blk, 0, stream>>>(x, xTh);

    // ================= Stage A: dict_conv(x, W1, stride 2) =================
    // c0 = relu(MU*conv(x) - shr) -> Pa
    conv_reg<3,2,1,0,128><<<gF, blk, 0, stream>>>(Af1, xTh, NFo, Pa, NH, NH, NF, NF, zp,
        256, 56, 56, 28, 28, 36, 196, MU_F, 0.f, -SHRINK_F, 1, 0);
    // shortcut: Psc = bnsc(conv1x1(x))
    conv_reg<1,2,0,0,128><<<gF, blk, 0, stream>>>(Afsc, xTh, NFo, Psc, NH, NH, bscs, bsct, zp,
        256, 56, 56, 28, 28, 4, 196, 1.f, 0.f, 0.f, 0, 0);

    // iter 1 (a = c0 = Pa): r = x - convT(a); c = relu(a + MU*conv(r) - shr)
    conv_reg<3,2,1,2,256><<<gT2, blk, 0, stream>>>(AfT1, Pa, NFo, r56h, xTh, NH, NF, NF, zp,
        128, 28, 28, 56, 56, 72, 196, -1.f, 1.f, 0.f, 0, 0);
    conv_reg<3,2,1,0,128><<<gF, blk, 0, stream>>>(Af1, r56h, NFo, Pb, Pa, NH, NF, NF, zp,
        256, 56, 56, 28, 28, 36, 196, MU_F, 1.f, -SHRINK_F, 1, 0);

    // iter 2
    comb_kernel<<<gC, blk, 0, stream>>>(Pb, Pa, Pc, 1.f + al[1], -al[1], n8);
    conv_reg<3,2,1,2,256><<<gT2, blk, 0, stream>>>(AfT1, Pc, NFo, r56h, xTh, NH, NF, NF, zp,
        128, 28, 28, 56, 56, 72, 196, -1.f, 1.f, 0.f, 0, 0);
    conv_reg<3,2,1,0,128><<<gF, blk, 0, stream>>>(Af1, r56h, NFo, Pa, Pc, NH, NF, NF, zp,
        256, 56, 56, 28, 28, 36, 196, MU_F, 1.f, -SHRINK_F, 1, 0);

    // iter 3 + fused BN1 -> y1 in Py
    comb_kernel<<<gC, blk, 0, stream>>>(Pa, Pb, Pc, 1.f + al[2], -al[2], n8);
    conv_reg<3,2,1,2,256><<<gT2, blk, 0, stream>>>(AfT1, Pc, NFo, r56h, xTh, NH, NF, NF, zp,
        128, 28, 28, 56, 56, 72, 196, -1.f, 1.f, 0.f, 0, 0);
    conv_reg<3,2,1,0,128><<<gF, blk, 0, stream>>>(Af1, r56h, NFo, Py, Pc, NH, bn1s, bn1t, zp,
        256, 56, 56, 28, 28, 36, 196, MU_F, 1.f, -SHRINK_F, 1, 0);

    // ================= Stage B: dict_conv(y1, W2, stride 1) ================
    conv_reg<3,1,1,0,256><<<gF, blk, 0, stream>>>(Af2, Py, NFo, Pa, NH, NH, NF, NF, zp,
        256, 28, 28, 28, 28, 72, 196, MU_F, 0.f, -SHRINK_F, 1, 0);

    // iter 1 (a = c0 = Pa)
    conv_reg<3,1,1,1,256><<<gF, blk, 0, stream>>>(AfT2, Pa, NFo, r28h, Py, NH, NF, NF, zp,
        256, 28, 28, 28, 28, 72, 196, -1.f, 1.f, 0.f, 0, 0);
    conv_reg<3,1,1,0,256><<<gF, blk, 0, stream>>>(Af2, r28h, NFo, Pb, Pa, NH, NF, NF, zp,
        256, 28, 28, 28, 28, 72, 196, MU_F, 1.f, -SHRINK_F, 1, 0);

    // iter 2
    comb_kernel<<<gC, blk, 0, stream>>>(Pb, Pa, Pc, 1.f + al[1], -al[1], n8);
    conv_reg<3,1,1,1,256><<<gF, blk, 0, stream>>>(AfT2, Pc, NFo, r28h, Py, NH, NF, NF, zp,
        256, 28, 28, 28, 28, 72, 196, -1.f, 1.f, 0.f, 0, 0);
    conv_reg<3,1,1,0,256><<<gF, blk, 0, stream>>>(Af2, r28h, NFo, Pa, Pc, NH, NF, NF, zp,
        256, 28, 28, 28, 28, 72, 196, MU_F, 1.f, -SHRINK_F, 1, 0);

    // iter 3 + BN2 + shortcut add + final relu -> d_out (fp32 NCHW)
    comb_kernel<<<gC, blk, 0, stream>>>(Pa, Pb, Pc, 1.f + al[2], -al[2], n8);
    conv_reg<3,1,1,1,256><<<gF, blk, 0, stream>>>(AfT2, Pc, NFo, r28h, Py, NH, NF, NF, zp,
        256, 28, 28, 28, 28, 72, 196, -1.f, 1.f, 0.f, 0, 0);
    conv_reg<3,1,1,0,256><<<gF, blk, 0, stream>>>(Af2, r28h, outp, NHo, Pc, Psc, bn2s, bn2t, zp,
        256, 28, 28, 28, 28, 72, 196, MU_F, 1.f, -SHRINK_F, 1, 1);
}